// Round 1
// baseline (238.386 us; speedup 1.0000x reference)
//
#include <hip/hip_runtime.h>

#define N_POST 50000
#define N_IN   17400
#define NNZ_E  1000000
#define T_DIM  64
#define R_DIM  5
#define NT_DIM 10
#define CHUNK  1024
#define NCHUNK ((N_POST + CHUNK - 1) / CHUNK)   // 49

// ---- x (64 x 17400) -> xT (17400 x 64): per-edge gather becomes one coalesced 256B row ----
__global__ void k_transpose(const float* __restrict__ x, float* __restrict__ xT) {
    int tid = blockIdx.x * blockDim.x + threadIdx.x;
    if (tid >= N_IN * T_DIM) return;
    int col = tid >> 6, t = tid & 63;
    xT[tid] = x[t * N_IN + col];
}

__global__ void k_zero(int* counts) {
    int tid = blockIdx.x * blockDim.x + threadIdx.x;
    if (tid < N_POST) counts[tid] = 0;
}

__global__ void k_hist(const int* __restrict__ idx, int* counts) {
    int e = blockIdx.x * blockDim.x + threadIdx.x;
    if (e < NNZ_E) atomicAdd(&counts[idx[2 * e]], 1);
}

// chunked exclusive scan: per-chunk scan + totals
__global__ void k_scanA(const int* __restrict__ counts, int* exc, int* totals) {
    __shared__ int buf[CHUNK];
    int tid = threadIdx.x;
    int gid = blockIdx.x * CHUNK + tid;
    int v = (gid < N_POST) ? counts[gid] : 0;
    buf[tid] = v;
    __syncthreads();
    for (int off = 1; off < CHUNK; off <<= 1) {
        int t = (tid >= off) ? buf[tid - off] : 0;
        __syncthreads();
        buf[tid] += t;
        __syncthreads();
    }
    if (gid < N_POST) exc[gid] = buf[tid] - v;
    if (tid == CHUNK - 1) totals[blockIdx.x] = buf[tid];
}

__global__ void k_scanB(const int* __restrict__ totals, int* base) {
    if (threadIdx.x == 0 && blockIdx.x == 0) {
        int run = 0;
        for (int i = 0; i < NCHUNK; i++) { base[i] = run; run += totals[i]; }
    }
}

__global__ void k_scanC(int* exc, const int* __restrict__ base, int* cursor) {
    int gid = blockIdx.x * CHUNK + threadIdx.x;
    if (gid < N_POST) {
        int v = exc[gid] + base[blockIdx.x];
        exc[gid] = v;
        cursor[gid] = v;
    }
}

// counting-sort scatter into compact records: packed (col | sid<<16), weight
__global__ void k_scatter(const int* __restrict__ idx, const float* __restrict__ iw,
                          const int* __restrict__ sid, int* cursor,
                          unsigned int* __restrict__ spk, float* __restrict__ sw) {
    int e = blockIdx.x * blockDim.x + threadIdx.x;
    if (e >= NNZ_E) return;
    int row = idx[2 * e], col = idx[2 * e + 1];
    int s = sid[e];
    int pos = atomicAdd(&cursor[row], 1);
    spk[pos] = (unsigned)col | ((unsigned)s << 16);
    sw[pos]  = iw[e];
}

// one wave per post-neuron; lane = time step; 5 accumulators per lane
__global__ __launch_bounds__(256) void k_phase2(
        const float* __restrict__ xT, const int* __restrict__ exc,
        const int* __restrict__ counts, const unsigned int* __restrict__ spk,
        const float* __restrict__ sw, const float* __restrict__ S,
        float* __restrict__ out) {
    __shared__ float s_lds[NT_DIM * R_DIM];
    if (threadIdx.x < NT_DIM * R_DIM) s_lds[threadIdx.x] = S[threadIdx.x];
    __syncthreads();
    int wave = threadIdx.x >> 6;
    int lane = threadIdx.x & 63;
    int p = blockIdx.x * 4 + wave;
    if (p >= N_POST) return;
    int start = exc[p];
    int n = counts[p];
    float acc0 = 0.f, acc1 = 0.f, acc2 = 0.f, acc3 = 0.f, acc4 = 0.f;
    for (int i = start; i < start + n; i++) {
        unsigned pk = spk[i];          // wave-uniform address -> broadcast
        float w = sw[i];
        int col = pk & 0xFFFF;
        int s = pk >> 16;
        float xv = xT[col * T_DIM + lane];   // coalesced 256B segment
        const float* f = &s_lds[s * R_DIM];
        acc0 += xv * (w * f[0]);
        acc1 += xv * (w * f[1]);
        acc2 += xv * (w * f[2]);
        acc3 += xv * (w * f[3]);
        acc4 += xv * (w * f[4]);
    }
    float* o = out + (size_t)lane * (N_POST * R_DIM) + (size_t)p * R_DIM;
    o[0] = acc0; o[1] = acc1; o[2] = acc2; o[3] = acc3; o[4] = acc4;
}

extern "C" void kernel_launch(void* const* d_in, const int* in_sizes, int n_in,
                              void* d_out, int out_size, void* d_ws, size_t ws_size,
                              hipStream_t stream) {
    const float* inp     = (const float*)d_in[0];
    const int*   indices = (const int*)d_in[1];
    const float* iw      = (const float*)d_in[2];
    const float* S       = (const float*)d_in[3];
    const int*   sid     = (const int*)d_in[4];
    float* out = (float*)d_out;

    char* ws = (char*)d_ws;
    size_t off = 0;
    auto alloc = [&](size_t bytes) -> void* {
        void* p = ws + off;
        off += (bytes + 255) & ~(size_t)255;
        return p;
    };
    float*    xT      = (float*)alloc((size_t)N_IN * T_DIM * 4);
    int*      counts  = (int*)alloc((size_t)N_POST * 4);
    int*      exc     = (int*)alloc((size_t)N_POST * 4);
    int*      totals  = (int*)alloc((size_t)NCHUNK * 4);
    int*      base    = (int*)alloc((size_t)NCHUNK * 4);
    int*      cursor  = (int*)alloc((size_t)N_POST * 4);
    unsigned* spk     = (unsigned*)alloc((size_t)NNZ_E * 4);
    float*    sw      = (float*)alloc((size_t)NNZ_E * 4);

    k_transpose<<<(N_IN * T_DIM + 255) / 256, 256, 0, stream>>>(inp, xT);
    k_zero<<<(N_POST + 255) / 256, 256, 0, stream>>>(counts);
    k_hist<<<(NNZ_E + 255) / 256, 256, 0, stream>>>(indices, counts);
    k_scanA<<<NCHUNK, CHUNK, 0, stream>>>(counts, exc, totals);
    k_scanB<<<1, 64, 0, stream>>>(totals, base);
    k_scanC<<<NCHUNK, CHUNK, 0, stream>>>(exc, base, cursor);
    k_scatter<<<(NNZ_E + 255) / 256, 256, 0, stream>>>(indices, iw, sid, cursor, spk, sw);
    k_phase2<<<(N_POST + 3) / 4, 256, 0, stream>>>(xT, exc, counts, spk, sw, S, out);
}

// Round 2
// 184.930 us; speedup vs baseline: 1.2891x; 1.2891x over previous
//
#include <hip/hip_runtime.h>

#define N_POST 50000
#define N_IN   17400
#define NNZ_E  1000000
#define T_DIM  64
#define R_DIM  5
#define NT_DIM 10
#define CHUNK  1024
#define NCHUNK ((N_POST + CHUNK - 1) / CHUNK)   // 49

#define TRANS_BLOCKS ((N_IN * T_DIM + 255) / 256)   // 4350
#define ZERO_BLOCKS  ((N_POST + 255) / 256)         // 196
#define EDGE_BLOCKS  ((NNZ_E + 255) / 256)          // 3907

// ---- fused: transpose x -> xT  AND  zero counts (independent work) ----
__global__ void k_trans_zero(const float* __restrict__ x, float* __restrict__ xT,
                             int* __restrict__ counts) {
    int b = blockIdx.x;
    if (b < TRANS_BLOCKS) {
        int tid = b * 256 + threadIdx.x;
        if (tid < N_IN * T_DIM) {
            int col = tid >> 6, t = tid & 63;
            xT[tid] = x[t * N_IN + col];
        }
    } else {
        int tid = (b - TRANS_BLOCKS) * 256 + threadIdx.x;
        if (tid < N_POST) counts[tid] = 0;
    }
}

__global__ void k_hist(const int2* __restrict__ idx2, int* counts) {
    int e = blockIdx.x * blockDim.x + threadIdx.x;
    if (e < NNZ_E) atomicAdd(&counts[idx2[e].x], 1);
}

// per-chunk inclusive scan -> local exclusive into cursor, chunk totals
__global__ void k_scanA(const int* __restrict__ counts, int* cursor, int* totals) {
    __shared__ int buf[CHUNK];
    int tid = threadIdx.x;
    int gid = blockIdx.x * CHUNK + tid;
    int v = (gid < N_POST) ? counts[gid] : 0;
    buf[tid] = v;
    __syncthreads();
    for (int off = 1; off < CHUNK; off <<= 1) {
        int t = (tid >= off) ? buf[tid - off] : 0;
        __syncthreads();
        buf[tid] += t;
        __syncthreads();
    }
    if (gid < N_POST) cursor[gid] = buf[tid] - v;
    if (tid == CHUNK - 1) totals[blockIdx.x] = buf[tid];
}

// add per-chunk base (computed by 64-lane reduce over totals[0..b-1])
__global__ void k_scanC(int* cursor, const int* __restrict__ totals) {
    __shared__ int sbase;
    int tid = threadIdx.x;
    if (tid < 64) {
        int v = (tid < (int)blockIdx.x) ? totals[tid] : 0;
        for (int off = 32; off; off >>= 1) v += __shfl_down(v, off);
        if (tid == 0) sbase = v;
    }
    __syncthreads();
    int gid = blockIdx.x * CHUNK + tid;
    if (gid < N_POST) cursor[gid] += sbase;
}

// counting-sort scatter: fused 8B records (col|sid<<16, weight-bits)
__global__ void k_scatter(const int2* __restrict__ idx2, const float* __restrict__ iw,
                          const int* __restrict__ sid, int* cursor,
                          uint2* __restrict__ rec) {
    int e = blockIdx.x * blockDim.x + threadIdx.x;
    if (e >= NNZ_E) return;
    int2 rc = idx2[e];
    int pos = atomicAdd(&cursor[rc.x], 1);
    rec[pos] = make_uint2((unsigned)rc.y | ((unsigned)sid[e] << 16),
                          __float_as_uint(iw[e]));
}

// 16 consecutive p per block (4 waves x 4 p); lane = t; LDS-staged coalesced writes
__global__ __launch_bounds__(256) void k_phase2(
        const float* __restrict__ xT, const int* __restrict__ cursor,
        const int* __restrict__ counts, const uint2* __restrict__ rec,
        const float* __restrict__ S, float* __restrict__ out) {
    __shared__ float s_lds[NT_DIM * R_DIM];
    __shared__ float o_lds[T_DIM * 81];      // [t][16p x 5r], pad 80->81
    int tid = threadIdx.x;
    if (tid < NT_DIM * R_DIM) s_lds[tid] = S[tid];
    __syncthreads();
    int wave = tid >> 6, lane = tid & 63;
    #pragma unroll
    for (int k = 0; k < 4; ++k) {
        int p = blockIdx.x * 16 + wave * 4 + k;
        int end = cursor[p];               // segment end after scatter
        int n = counts[p];
        int i = end - n;                   // segment start
        float a0 = 0.f, a1 = 0.f, a2 = 0.f, a3 = 0.f, a4 = 0.f;
        if (i < end) {
            uint2 rc = rec[i];
            for (++i; i < end; ++i) {
                uint2 rn = rec[i];                         // next record in flight
                float w = __uint_as_float(rc.y);
                int col = rc.x & 0xFFFF;
                const float* f = &s_lds[(rc.x >> 16) * R_DIM];
                float xv = xT[col * T_DIM + lane];
                a0 += xv * (w * f[0]);
                a1 += xv * (w * f[1]);
                a2 += xv * (w * f[2]);
                a3 += xv * (w * f[3]);
                a4 += xv * (w * f[4]);
                rc = rn;
            }
            float w = __uint_as_float(rc.y);
            int col = rc.x & 0xFFFF;
            const float* f = &s_lds[(rc.x >> 16) * R_DIM];
            float xv = xT[col * T_DIM + lane];
            a0 += xv * (w * f[0]);
            a1 += xv * (w * f[1]);
            a2 += xv * (w * f[2]);
            a3 += xv * (w * f[3]);
            a4 += xv * (w * f[4]);
        }
        float* d = &o_lds[lane * 81 + (wave * 4 + k) * 5];
        d[0] = a0; d[1] = a1; d[2] = a2; d[3] = a3; d[4] = a4;
    }
    __syncthreads();
    int base5 = blockIdx.x * 80;           // byte offset 320*b -> 64B-aligned
    for (int i2 = tid; i2 < T_DIM * 80; i2 += 256) {
        int t = i2 / 80;
        int j = i2 - t * 80;
        out[(size_t)t * (N_POST * R_DIM) + base5 + j] = o_lds[t * 81 + j];
    }
}

extern "C" void kernel_launch(void* const* d_in, const int* in_sizes, int n_in,
                              void* d_out, int out_size, void* d_ws, size_t ws_size,
                              hipStream_t stream) {
    const float* inp     = (const float*)d_in[0];
    const int2*  idx2    = (const int2*)d_in[1];
    const float* iw      = (const float*)d_in[2];
    const float* S       = (const float*)d_in[3];
    const int*   sid     = (const int*)d_in[4];
    float* out = (float*)d_out;

    char* ws = (char*)d_ws;
    size_t off = 0;
    auto alloc = [&](size_t bytes) -> void* {
        void* p = ws + off;
        off += (bytes + 255) & ~(size_t)255;
        return p;
    };
    float* xT     = (float*)alloc((size_t)N_IN * T_DIM * 4);
    int*   counts = (int*)alloc((size_t)N_POST * 4);
    int*   cursor = (int*)alloc((size_t)N_POST * 4);
    int*   totals = (int*)alloc((size_t)NCHUNK * 4);
    uint2* rec    = (uint2*)alloc((size_t)NNZ_E * 8);

    k_trans_zero<<<TRANS_BLOCKS + ZERO_BLOCKS, 256, 0, stream>>>(inp, xT, counts);
    k_hist<<<EDGE_BLOCKS, 256, 0, stream>>>(idx2, counts);
    k_scanA<<<NCHUNK, CHUNK, 0, stream>>>(counts, cursor, totals);
    k_scanC<<<NCHUNK, CHUNK, 0, stream>>>(cursor, totals);
    k_scatter<<<EDGE_BLOCKS, 256, 0, stream>>>(idx2, iw, sid, cursor, rec);
    k_phase2<<<N_POST / 16, 256, 0, stream>>>(xT, cursor, counts, rec, S, out);
}

// Round 3
// 131.474 us; speedup vs baseline: 1.8132x; 1.4066x over previous
//
#include <hip/hip_runtime.h>

#define N_POST 50000
#define N_IN   17400
#define NNZ_E  1000000
#define T_DIM  64
#define R_DIM  5
#define NT_DIM 10

#define BROWS  256                                  // rows per bucket
#define NBUCK  ((N_POST + BROWS - 1) / BROWS)       // 196
#define EPB    4096                                 // edges per split block
#define NBLK1  ((NNZ_E + EPB - 1) / EPB)            // 245

#define TRANS_BLOCKS ((N_IN * T_DIM + 255) / 256)   // 4350

// ---- transpose x -> xT (coalesced per-edge gathers later) + zero bucket hist ----
__global__ void k_trans_zero(const float* __restrict__ x, float* __restrict__ xT,
                             int* __restrict__ bhist) {
    int b = blockIdx.x;
    if (b < TRANS_BLOCKS) {
        int tid = b * 256 + threadIdx.x;
        if (tid < N_IN * T_DIM) {
            int col = tid >> 6, t = tid & 63;
            xT[tid] = x[t * N_IN + col];
        }
    } else {
        if (threadIdx.x < NBUCK) bhist[threadIdx.x] = 0;
    }
}

// ---- coarse bucket histogram: LDS hist, one global atomic per bucket per block ----
__global__ __launch_bounds__(256) void k_bhist(const int2* __restrict__ idx2,
                                               int* __restrict__ bhist) {
    __shared__ int lh[NBUCK];
    int t = threadIdx.x;
    for (int i = t; i < NBUCK; i += 256) lh[i] = 0;
    __syncthreads();
    int base = blockIdx.x * EPB;
    int end = min(base + EPB, NNZ_E);
    for (int i = base + t; i < end; i += 256)
        atomicAdd(&lh[(unsigned)idx2[i].x >> 8], 1);
    __syncthreads();
    for (int i = t; i < NBUCK; i += 256)
        if (lh[i]) atomicAdd(&bhist[i], lh[i]);
}

// ---- tiny scan over 196 buckets -> bbase[0..196], init gcur, set row_start tail ----
__global__ void k_bscan(const int* __restrict__ bhist, int* __restrict__ bbase,
                        int* __restrict__ gcur, int* __restrict__ row_start) {
    __shared__ int buf[256];
    int t = threadIdx.x;
    int v = (t < NBUCK) ? bhist[t] : 0;
    buf[t] = v;
    __syncthreads();
    for (int off = 1; off < 256; off <<= 1) {
        int u = (t >= off) ? buf[t - off] : 0;
        __syncthreads();
        buf[t] += u;
        __syncthreads();
    }
    if (t <= NBUCK) bbase[t] = buf[t] - v;     // exclusive (v=0 for t==NBUCK)
    if (t < NBUCK)  gcur[t] = buf[t] - v;
    if (t == 0) row_start[N_POST] = NNZ_E;
}

// ---- pass 1: block-local counting sort by bucket, bucket-major coalesced flush ----
// record: x = col(15b) | sid<<15 (4b) | row_low<<19 (8b) ; y = weight bits
__global__ __launch_bounds__(256) void k_split(const int2* __restrict__ idx2,
                                               const float* __restrict__ iw,
                                               const int* __restrict__ sid,
                                               int* __restrict__ gcur,
                                               uint2* __restrict__ rec1) {
    __shared__ uint2 lsrc[EPB];                 // 32 KB
    __shared__ uint2 ldst[EPB];                 // 32 KB
    __shared__ unsigned char bsrc[EPB];         // 4 KB
    __shared__ unsigned char bdst[EPB];         // 4 KB
    __shared__ int lhist[256];
    __shared__ int lsc[256];
    __shared__ int lbase[256];
    __shared__ int lcur[256];
    __shared__ int gbase[NBUCK];
    int t = threadIdx.x;
    lhist[t] = 0;
    __syncthreads();
    int base = blockIdx.x * EPB;
    int n = min(EPB, NNZ_E - base);
    for (int i = t; i < n; i += 256) {
        int2 rc = idx2[base + i];
        unsigned b = (unsigned)rc.x >> 8;
        unsigned x = (unsigned)rc.y | ((unsigned)sid[base + i] << 15)
                   | ((unsigned)(rc.x & 255) << 19);
        lsrc[i] = make_uint2(x, __float_as_uint(iw[base + i]));
        bsrc[i] = (unsigned char)b;
        atomicAdd(&lhist[b], 1);
    }
    __syncthreads();
    int v = lhist[t];
    lsc[t] = v;
    __syncthreads();
    for (int off = 1; off < 256; off <<= 1) {
        int u = (t >= off) ? lsc[t - off] : 0;
        __syncthreads();
        lsc[t] += u;
        __syncthreads();
    }
    int excl = lsc[t] - v;
    lbase[t] = excl;
    lcur[t] = excl;
    if (t < NBUCK && v > 0) gbase[t] = atomicAdd(&gcur[t], v);
    __syncthreads();
    for (int i = t; i < n; i += 256) {
        int b = bsrc[i];
        int pos = atomicAdd(&lcur[b], 1);
        ldst[pos] = lsrc[i];
        bdst[pos] = (unsigned char)b;
    }
    __syncthreads();
    for (int i = t; i < n; i += 256) {
        int b = bdst[i];
        rec1[gbase[b] + (i - lbase[b])] = ldst[i];   // coalesced runs
    }
}

// ---- pass 2: per-bucket fine sort by row; writes row_start; L2-confined scatter ----
__global__ __launch_bounds__(256) void k_fine(const uint2* __restrict__ rec1,
                                              const int* __restrict__ bbase,
                                              uint2* __restrict__ rec,
                                              int* __restrict__ row_start) {
    __shared__ int lhist[BROWS];
    __shared__ int lsc[BROWS];
    __shared__ int lcur[BROWS];
    int t = threadIdx.x;
    int b = blockIdx.x;
    int s0 = bbase[b], s1 = bbase[b + 1];
    lhist[t] = 0;
    __syncthreads();
    for (int i = s0 + t; i < s1; i += 256)
        atomicAdd(&lhist[(rec1[i].x >> 19) & 255], 1);
    __syncthreads();
    int v = lhist[t];
    lsc[t] = v;
    __syncthreads();
    for (int off = 1; off < 256; off <<= 1) {
        int u = (t >= off) ? lsc[t - off] : 0;
        __syncthreads();
        lsc[t] += u;
        __syncthreads();
    }
    int excl = lsc[t] - v;
    int p = b * BROWS + t;
    if (p < N_POST) row_start[p] = s0 + excl;
    lcur[t] = excl;
    __syncthreads();
    for (int i = s0 + t; i < s1; i += 256) {
        uint2 rc = rec1[i];
        int r = (rc.x >> 19) & 255;
        int pos = atomicAdd(&lcur[r], 1);
        rec[s0 + pos] = rc;                      // random 8B but within ~41KB region
    }
}

// ---- 16 consecutive p per block (4 waves x 4 p); lane = t; LDS-staged writes ----
__global__ __launch_bounds__(256) void k_phase2(
        const float* __restrict__ xT, const int* __restrict__ row_start,
        const uint2* __restrict__ rec, const float* __restrict__ S,
        float* __restrict__ out) {
    __shared__ float s_lds[NT_DIM * R_DIM];
    __shared__ float o_lds[T_DIM * 81];
    int tid = threadIdx.x;
    if (tid < NT_DIM * R_DIM) s_lds[tid] = S[tid];
    __syncthreads();
    int wave = tid >> 6, lane = tid & 63;
    #pragma unroll
    for (int k = 0; k < 4; ++k) {
        int p = blockIdx.x * 16 + wave * 4 + k;
        int i = row_start[p];
        int end = row_start[p + 1];
        float a0 = 0.f, a1 = 0.f, a2 = 0.f, a3 = 0.f, a4 = 0.f;
        if (i < end) {
            uint2 rc = rec[i];
            for (++i; i < end; ++i) {
                uint2 rn = rec[i];
                float w = __uint_as_float(rc.y);
                int col = rc.x & 0x7FFF;
                const float* f = &s_lds[((rc.x >> 15) & 0xF) * R_DIM];
                float xv = xT[col * T_DIM + lane];
                a0 += xv * (w * f[0]);
                a1 += xv * (w * f[1]);
                a2 += xv * (w * f[2]);
                a3 += xv * (w * f[3]);
                a4 += xv * (w * f[4]);
                rc = rn;
            }
            float w = __uint_as_float(rc.y);
            int col = rc.x & 0x7FFF;
            const float* f = &s_lds[((rc.x >> 15) & 0xF) * R_DIM];
            float xv = xT[col * T_DIM + lane];
            a0 += xv * (w * f[0]);
            a1 += xv * (w * f[1]);
            a2 += xv * (w * f[2]);
            a3 += xv * (w * f[3]);
            a4 += xv * (w * f[4]);
        }
        float* d = &o_lds[lane * 81 + (wave * 4 + k) * 5];
        d[0] = a0; d[1] = a1; d[2] = a2; d[3] = a3; d[4] = a4;
    }
    __syncthreads();
    int base5 = blockIdx.x * 80;
    for (int i2 = tid; i2 < T_DIM * 80; i2 += 256) {
        int t = i2 / 80;
        int j = i2 - t * 80;
        out[(size_t)t * (N_POST * R_DIM) + base5 + j] = o_lds[t * 81 + j];
    }
}

extern "C" void kernel_launch(void* const* d_in, const int* in_sizes, int n_in,
                              void* d_out, int out_size, void* d_ws, size_t ws_size,
                              hipStream_t stream) {
    const float* inp  = (const float*)d_in[0];
    const int2*  idx2 = (const int2*)d_in[1];
    const float* iw   = (const float*)d_in[2];
    const float* S    = (const float*)d_in[3];
    const int*   sid  = (const int*)d_in[4];
    float* out = (float*)d_out;

    char* ws = (char*)d_ws;
    size_t off = 0;
    auto alloc = [&](size_t bytes) -> void* {
        void* p = ws + off;
        off += (bytes + 255) & ~(size_t)255;
        return p;
    };
    float* xT        = (float*)alloc((size_t)N_IN * T_DIM * 4);
    int*   bhist     = (int*)alloc((size_t)NBUCK * 4);
    int*   bbase     = (int*)alloc((size_t)(NBUCK + 1) * 4);
    int*   gcur      = (int*)alloc((size_t)NBUCK * 4);
    int*   row_start = (int*)alloc((size_t)(N_POST + 1) * 4);
    uint2* rec1      = (uint2*)alloc((size_t)NNZ_E * 8);
    uint2* rec       = (uint2*)alloc((size_t)NNZ_E * 8);

    k_trans_zero<<<TRANS_BLOCKS + 1, 256, 0, stream>>>(inp, xT, bhist);
    k_bhist<<<NBLK1, 256, 0, stream>>>(idx2, bhist);
    k_bscan<<<1, 256, 0, stream>>>(bhist, bbase, gcur, row_start);
    k_split<<<NBLK1, 256, 0, stream>>>(idx2, iw, sid, gcur, rec1);
    k_fine<<<NBUCK, 256, 0, stream>>>(rec1, bbase, rec, row_start);
    k_phase2<<<N_POST / 16, 256, 0, stream>>>(xT, row_start, rec, S, out);
}

// Round 4
// 105.694 us; speedup vs baseline: 2.2554x; 1.2439x over previous
//
#include <hip/hip_runtime.h>

#define N_POST 50000
#define N_IN   17400
#define NNZ_E  1000000
#define T_DIM  64
#define R_DIM  5
#define NT_DIM 10

#define BROWS  256                                  // rows per bucket
#define NBUCK  ((N_POST + BROWS - 1) / BROWS)       // 196
#define EPB    4096                                 // edges per split block
#define NBLK1  ((NNZ_E + EPB - 1) / EPB)            // 245

#define TRANS_BLOCKS ((N_IN * T_DIM + 255) / 256)   // 4350

// ---- transpose x -> xT + zero bucket hist ----
__global__ void k_trans_zero(const float* __restrict__ x, float* __restrict__ xT,
                             int* __restrict__ bhist) {
    int b = blockIdx.x;
    if (b < TRANS_BLOCKS) {
        int tid = b * 256 + threadIdx.x;
        if (tid < N_IN * T_DIM) {
            int col = tid >> 6, t = tid & 63;
            xT[tid] = x[t * N_IN + col];
        }
    } else {
        if (threadIdx.x < NBUCK) bhist[threadIdx.x] = 0;
    }
}

// ---- coarse bucket histogram ----
__global__ __launch_bounds__(256) void k_bhist(const int2* __restrict__ idx2,
                                               int* __restrict__ bhist) {
    __shared__ int lh[NBUCK];
    int t = threadIdx.x;
    for (int i = t; i < NBUCK; i += 256) lh[i] = 0;
    __syncthreads();
    int base = blockIdx.x * EPB;
    int end = min(base + EPB, NNZ_E);
    for (int i = base + t; i < end; i += 256)
        atomicAdd(&lh[(unsigned)idx2[i].x >> 8], 1);
    __syncthreads();
    for (int i = t; i < NBUCK; i += 256)
        if (lh[i]) atomicAdd(&bhist[i], lh[i]);
}

// ---- tiny scan over buckets ----
__global__ void k_bscan(const int* __restrict__ bhist, int* __restrict__ bbase,
                        int* __restrict__ gcur, int* __restrict__ row_start) {
    __shared__ int buf[256];
    int t = threadIdx.x;
    int v = (t < NBUCK) ? bhist[t] : 0;
    buf[t] = v;
    __syncthreads();
    for (int off = 1; off < 256; off <<= 1) {
        int u = (t >= off) ? buf[t - off] : 0;
        __syncthreads();
        buf[t] += u;
        __syncthreads();
    }
    if (t <= NBUCK) bbase[t] = buf[t] - v;
    if (t < NBUCK)  gcur[t] = buf[t] - v;
    if (t == 0) row_start[N_POST] = NNZ_E;
}

// ---- pass 1: block-local counting sort by bucket, bucket-major coalesced flush ----
// record: x = col(15b) | sid<<15 (4b) | row_low<<19 (8b) ; y = weight bits
__global__ __launch_bounds__(256) void k_split(const int2* __restrict__ idx2,
                                               const float* __restrict__ iw,
                                               const int* __restrict__ sid,
                                               int* __restrict__ gcur,
                                               uint2* __restrict__ rec1) {
    __shared__ uint2 lsrc[EPB];
    __shared__ uint2 ldst[EPB];
    __shared__ unsigned char bsrc[EPB];
    __shared__ unsigned char bdst[EPB];
    __shared__ int lhist[256];
    __shared__ int lsc[256];
    __shared__ int lbase[256];
    __shared__ int lcur[256];
    __shared__ int gbase[NBUCK];
    int t = threadIdx.x;
    lhist[t] = 0;
    __syncthreads();
    int base = blockIdx.x * EPB;
    int n = min(EPB, NNZ_E - base);
    for (int i = t; i < n; i += 256) {
        int2 rc = idx2[base + i];
        unsigned b = (unsigned)rc.x >> 8;
        unsigned x = (unsigned)rc.y | ((unsigned)sid[base + i] << 15)
                   | ((unsigned)(rc.x & 255) << 19);
        lsrc[i] = make_uint2(x, __float_as_uint(iw[base + i]));
        bsrc[i] = (unsigned char)b;
        atomicAdd(&lhist[b], 1);
    }
    __syncthreads();
    int v = lhist[t];
    lsc[t] = v;
    __syncthreads();
    for (int off = 1; off < 256; off <<= 1) {
        int u = (t >= off) ? lsc[t - off] : 0;
        __syncthreads();
        lsc[t] += u;
        __syncthreads();
    }
    int excl = lsc[t] - v;
    lbase[t] = excl;
    lcur[t] = excl;
    if (t < NBUCK && v > 0) gbase[t] = atomicAdd(&gcur[t], v);
    __syncthreads();
    for (int i = t; i < n; i += 256) {
        int b = bsrc[i];
        int pos = atomicAdd(&lcur[b], 1);
        ldst[pos] = lsrc[i];
        bdst[pos] = (unsigned char)b;
    }
    __syncthreads();
    for (int i = t; i < n; i += 256) {
        int b = bdst[i];
        rec1[gbase[b] + (i - lbase[b])] = ldst[i];
    }
}

// ---- pass 2: per-bucket fine sort by row; writes row_start ----
__global__ __launch_bounds__(256) void k_fine(const uint2* __restrict__ rec1,
                                              const int* __restrict__ bbase,
                                              uint2* __restrict__ rec,
                                              int* __restrict__ row_start) {
    __shared__ int lhist[BROWS];
    __shared__ int lsc[BROWS];
    __shared__ int lcur[BROWS];
    int t = threadIdx.x;
    int b = blockIdx.x;
    int s0 = bbase[b], s1 = bbase[b + 1];
    lhist[t] = 0;
    __syncthreads();
    for (int i = s0 + t; i < s1; i += 256)
        atomicAdd(&lhist[(rec1[i].x >> 19) & 255], 1);
    __syncthreads();
    int v = lhist[t];
    lsc[t] = v;
    __syncthreads();
    for (int off = 1; off < 256; off <<= 1) {
        int u = (t >= off) ? lsc[t - off] : 0;
        __syncthreads();
        lsc[t] += u;
        __syncthreads();
    }
    int excl = lsc[t] - v;
    int p = b * BROWS + t;
    if (p < N_POST) row_start[p] = s0 + excl;
    lcur[t] = excl;
    __syncthreads();
    for (int i = s0 + t; i < s1; i += 256) {
        uint2 rc = rec1[i];
        int r = (rc.x >> 19) & 255;
        int pos = atomicAdd(&lcur[r], 1);
        rec[s0 + pos] = rc;
    }
}

#define FMA5(rc, xv)                                                         \
    do {                                                                     \
        float w_ = __uint_as_float((rc).y);                                  \
        const float* f_ = &s_lds[(((rc).x >> 15) & 0xF) * R_DIM];            \
        a0 += (xv) * (w_ * f_[0]);                                           \
        a1 += (xv) * (w_ * f_[1]);                                           \
        a2 += (xv) * (w_ * f_[2]);                                           \
        a3 += (xv) * (w_ * f_[3]);                                           \
        a4 += (xv) * (w_ * f_[4]);                                           \
    } while (0)

// ---- phase2: 16 consecutive p per block; lane = t; 4-edge SW pipeline ----
__global__ __launch_bounds__(256) void k_phase2(
        const float* __restrict__ xT, const int* __restrict__ row_start,
        const uint2* __restrict__ rec, const float* __restrict__ S,
        float* __restrict__ out) {
    __shared__ float s_lds[NT_DIM * R_DIM];
    __shared__ float o_lds[T_DIM * 81];
    int tid = threadIdx.x;
    if (tid < NT_DIM * R_DIM) s_lds[tid] = S[tid];
    __syncthreads();
    int wave = tid >> 6, lane = tid & 63;
    #pragma unroll
    for (int k = 0; k < 4; ++k) {
        int p = blockIdx.x * 16 + wave * 4 + k;
        int i = row_start[p];
        int end = row_start[p + 1];
        float a0 = 0.f, a1 = 0.f, a2 = 0.f, a3 = 0.f, a4 = 0.f;
        if (i + 4 <= end) {
            uint2 c0 = rec[i], c1 = rec[i + 1], c2 = rec[i + 2], c3 = rec[i + 3];
            float x0 = xT[(c0.x & 0x7FFF) * T_DIM + lane];
            float x1 = xT[(c1.x & 0x7FFF) * T_DIM + lane];
            float x2 = xT[(c2.x & 0x7FFF) * T_DIM + lane];
            float x3 = xT[(c3.x & 0x7FFF) * T_DIM + lane];
            i += 4;
            for (; i + 4 <= end; i += 4) {
                uint2 d0 = rec[i], d1 = rec[i + 1], d2 = rec[i + 2], d3 = rec[i + 3];
                float y0 = xT[(d0.x & 0x7FFF) * T_DIM + lane];
                float y1 = xT[(d1.x & 0x7FFF) * T_DIM + lane];
                float y2 = xT[(d2.x & 0x7FFF) * T_DIM + lane];
                float y3 = xT[(d3.x & 0x7FFF) * T_DIM + lane];
                FMA5(c0, x0);
                FMA5(c1, x1);
                FMA5(c2, x2);
                FMA5(c3, x3);
                c0 = d0; c1 = d1; c2 = d2; c3 = d3;
                x0 = y0; x1 = y1; x2 = y2; x3 = y3;
            }
            FMA5(c0, x0);
            FMA5(c1, x1);
            FMA5(c2, x2);
            FMA5(c3, x3);
        }
        for (; i < end; ++i) {
            uint2 rc = rec[i];
            float xv = xT[(rc.x & 0x7FFF) * T_DIM + lane];
            FMA5(rc, xv);
        }
        float* d = &o_lds[lane * 81 + (wave * 4 + k) * 5];
        d[0] = a0; d[1] = a1; d[2] = a2; d[3] = a3; d[4] = a4;
    }
    __syncthreads();
    int base5 = blockIdx.x * 80;
    for (int i2 = tid; i2 < T_DIM * 80; i2 += 256) {
        int t = i2 / 80;
        int j = i2 - t * 80;
        out[(size_t)t * (N_POST * R_DIM) + base5 + j] = o_lds[t * 81 + j];
    }
}

extern "C" void kernel_launch(void* const* d_in, const int* in_sizes, int n_in,
                              void* d_out, int out_size, void* d_ws, size_t ws_size,
                              hipStream_t stream) {
    const float* inp  = (const float*)d_in[0];
    const int2*  idx2 = (const int2*)d_in[1];
    const float* iw   = (const float*)d_in[2];
    const float* S    = (const float*)d_in[3];
    const int*   sid  = (const int*)d_in[4];
    float* out = (float*)d_out;

    char* ws = (char*)d_ws;
    size_t off = 0;
    auto alloc = [&](size_t bytes) -> void* {
        void* p = ws + off;
        off += (bytes + 255) & ~(size_t)255;
        return p;
    };
    float* xT        = (float*)alloc((size_t)N_IN * T_DIM * 4);
    int*   bhist     = (int*)alloc((size_t)NBUCK * 4);
    int*   bbase     = (int*)alloc((size_t)(NBUCK + 1) * 4);
    int*   gcur      = (int*)alloc((size_t)NBUCK * 4);
    int*   row_start = (int*)alloc((size_t)(N_POST + 1) * 4);
    uint2* rec1      = (uint2*)alloc((size_t)NNZ_E * 8);
    uint2* rec       = (uint2*)alloc((size_t)NNZ_E * 8);

    k_trans_zero<<<TRANS_BLOCKS + 1, 256, 0, stream>>>(inp, xT, bhist);
    k_bhist<<<NBLK1, 256, 0, stream>>>(idx2, bhist);
    k_bscan<<<1, 256, 0, stream>>>(bhist, bbase, gcur, row_start);
    k_split<<<NBLK1, 256, 0, stream>>>(idx2, iw, sid, gcur, rec1);
    k_fine<<<NBUCK, 256, 0, stream>>>(rec1, bbase, rec, row_start);
    k_phase2<<<N_POST / 16, 256, 0, stream>>>(xT, row_start, rec, S, out);
}